// Round 2
// baseline (1076.608 us; speedup 1.0000x reference)
//
#include <hip/hip_runtime.h>
#include <hip/hip_bf16.h>

// HashRoutedSSMLayer: B=8,S=2048,D=1024,N=256,H=512,E=8
// fp32 inputs (x, Win, Wsin, Wsout, Wout, dparam), int32 token_ids, fp32 out.
// Pipeline: route -> offsets/tiles -> stable sort -> GEMM12(U,SH) ->
//           GEMM3(a,w,c,skip) -> scan(y) -> GEMM4(out, scatter)

#define TOKS 16384
#define DD   1024
#define NN   256
#define HH   512
#define EE   8
#define MAXTILES 264   // sum ceil(cnt_e/64) <= 256 + 8

__device__ __forceinline__ int route_of(int token) {
    unsigned x = (unsigned)token;
    x ^= x >> 16; x *= 2246822507u; x ^= x >> 13; x *= 3266489909u; x ^= x >> 16;
    return (int)(x & 7u);
}
__device__ __forceinline__ float sigm(float v) { return 1.0f / (1.0f + __expf(-v)); }

// ---------------- K1: per-row route histogram ----------------
__global__ void k_route(const int* __restrict__ tok, int* __restrict__ cnt) {
    int b = blockIdx.x, tid = threadIdx.x;
    __shared__ int lc[256 * 8];
    #pragma unroll
    for (int e = 0; e < 8; e++) lc[tid * 8 + e] = 0;
    #pragma unroll
    for (int i = 0; i < 8; i++) {
        int s = tid * 8 + i;
        int e = route_of(tok[b * 2048 + s]);
        lc[tid * 8 + e]++;
    }
    __syncthreads();
    if (tid < 8) {
        int s = 0;
        for (int t = 0; t < 256; t++) s += lc[t * 8 + tid];
        cnt[b * 8 + tid] = s;
    }
}

// ---------------- K2: offsets + tile table ----------------
__global__ void k_offsets(const int* __restrict__ cnt, int* __restrict__ grpoff,
                          int* __restrict__ tileE, int* __restrict__ tileS,
                          int* __restrict__ tileR, int* __restrict__ meta) {
    __shared__ int sc[64];
    __shared__ int ce[8];
    __shared__ int eoff[9];
    int tid = threadIdx.x;
    if (tid < 64) sc[tid] = cnt[tid];
    __syncthreads();
    if (tid < 8) {
        int s = 0;
        for (int b = 0; b < 8; b++) s += sc[b * 8 + tid];
        ce[tid] = s;
    }
    __syncthreads();
    if (tid == 0) {
        eoff[0] = 0;
        for (int e = 0; e < 8; e++) eoff[e + 1] = eoff[e] + ce[e];
    }
    __syncthreads();
    if (tid < 64) {
        int b = tid >> 3, e = tid & 7;
        int run = eoff[e];
        for (int b2 = 0; b2 < b; b2++) run += sc[b2 * 8 + e];
        grpoff[b * 8 + e] = run;
    }
    if (tid == 0) {
        int idx = 0;
        for (int e = 0; e < 8; e++) {
            int c = ce[e], st = eoff[e];
            for (int i = 0; i < c; i += 64) {
                tileE[idx] = e;
                tileS[idx] = st + i;
                tileR[idx] = (c - i < 64) ? (c - i) : 64;
                idx++;
            }
        }
        meta[0] = idx;
    }
}

// ---------------- K3: stable counting-sort scatter ----------------
__global__ void k_scatter(const int* __restrict__ tok, const int* __restrict__ grpoff,
                          int* __restrict__ perm) {
    int b = blockIdx.x, tid = threadIdx.x;
    __shared__ int lh[8 * 256];
    int r[8];
    int myc[8] = {0, 0, 0, 0, 0, 0, 0, 0};
    #pragma unroll
    for (int i = 0; i < 8; i++) {
        int s = tid * 8 + i;
        int e = route_of(tok[b * 2048 + s]);
        r[i] = e; myc[e]++;
    }
    #pragma unroll
    for (int e = 0; e < 8; e++) lh[e * 256 + tid] = myc[e];
    __syncthreads();
    for (int e = 0; e < 8; e++) {
        for (int off = 1; off < 256; off <<= 1) {
            int add = (tid >= off) ? lh[e * 256 + tid - off] : 0;
            __syncthreads();
            lh[e * 256 + tid] += add;
            __syncthreads();
        }
    }
    int basep[8];
    #pragma unroll
    for (int e = 0; e < 8; e++) basep[e] = grpoff[b * 8 + e] + lh[e * 256 + tid] - myc[e];
    #pragma unroll
    for (int i = 0; i < 8; i++) {
        int e = r[i];
        perm[basep[e]++] = b * 2048 + tid * 8 + i;
    }
}

// ---------------- K4/K5/K7: generic grouped GEMM (64x64 tile, K-tile 16, fp32) ----------------
// mode 0: A = gathered x (K=1024), B = [Win|Wsin], epi: U / silu->SH  (gridY=12)
// mode 1: A = SH (K=512), B = Wsout, epi: a,w,c,skip                  (gridY=16)
// mode 2: A = Y(=U) (K=256), B = Wout, epi: scatter out               (gridY=16)
__global__ __launch_bounds__(256)
void k_gemm(int mode, int Kdim,
            const float* __restrict__ x,
            const int* __restrict__ perm,
            const float* __restrict__ Win,
            const float* __restrict__ Wsin,
            const float* __restrict__ Wsout,
            const float* __restrict__ Wout,
            const float* __restrict__ dparam,
            float* __restrict__ U, float* __restrict__ SH,
            float* __restrict__ Aa, float* __restrict__ Wg,
            float* __restrict__ Cc, float* __restrict__ Sk,
            float* __restrict__ out,
            const int* __restrict__ tileE, const int* __restrict__ tileS,
            const int* __restrict__ tileR, const int* __restrict__ meta) {
    int mt = blockIdx.x;
    if (mt >= meta[0]) return;
    int e = tileE[mt];
    int pos0 = tileS[mt];
    int rows = tileR[mt];
    int col0 = blockIdx.y * 64;
    int tid = threadIdx.x;
    int lrow = tid >> 2;          // 0..63 (tile row for A, tile col for B)
    int lk = (tid & 3) * 4;       // 0,4,8,12
    int tx = tid & 15, ty = tid >> 4;

    __shared__ float As[16][68];
    __shared__ float Bs[16][68];

    // hoisted row pointers
    const float* arow = nullptr;
    bool avalid = (lrow < rows);
    if (avalid) {
        if (mode == 0) {
            int t = perm[pos0 + lrow];
            arow = x + (size_t)t * DD;
        } else if (mode == 1) {
            arow = SH + (size_t)(pos0 + lrow) * HH;
        } else {
            arow = U + (size_t)(pos0 + lrow) * NN;
        }
    }
    int jg = col0 + lrow;  // global output column for the B row this thread stages
    const float* brow;
    if (mode == 0) {
        brow = (jg < 256) ? (Win + (size_t)(e * 256 + jg) * DD)
                          : (Wsin + (size_t)(e * 512 + (jg - 256)) * DD);
    } else if (mode == 1) {
        brow = Wsout + (size_t)(e * 1024 + jg) * HH;
    } else {
        brow = Wout + (size_t)(e * 1024 + jg) * NN;
    }

    float acc[4][4];
    #pragma unroll
    for (int i = 0; i < 4; i++)
        #pragma unroll
        for (int j = 0; j < 4; j++) acc[i][j] = 0.0f;

    for (int k0 = 0; k0 < Kdim; k0 += 16) {
        float4 fa = make_float4(0.f, 0.f, 0.f, 0.f);
        if (avalid) fa = *(const float4*)(arow + k0 + lk);
        float4 fb = *(const float4*)(brow + k0 + lk);
        __syncthreads();  // previous compute done before LDS overwrite
        As[lk + 0][lrow] = fa.x; As[lk + 1][lrow] = fa.y;
        As[lk + 2][lrow] = fa.z; As[lk + 3][lrow] = fa.w;
        Bs[lk + 0][lrow] = fb.x; Bs[lk + 1][lrow] = fb.y;
        Bs[lk + 2][lrow] = fb.z; Bs[lk + 3][lrow] = fb.w;
        __syncthreads();
        #pragma unroll
        for (int kk = 0; kk < 16; kk++) {
            const float4 av = *(const float4*)(&As[kk][ty * 4]);
            const float4 bv = *(const float4*)(&Bs[kk][tx * 4]);
            const float aa[4] = {av.x, av.y, av.z, av.w};
            const float bb[4] = {bv.x, bv.y, bv.z, bv.w};
            #pragma unroll
            for (int i = 0; i < 4; i++)
                #pragma unroll
                for (int j = 0; j < 4; j++)
                    acc[i][j] = fmaf(aa[i], bb[j], acc[i][j]);
        }
    }

    // epilogues
    if (mode == 0) {
        bool isU = (col0 < 256);
        #pragma unroll
        for (int i = 0; i < 4; i++) {
            int m = ty * 4 + i;
            if (m >= rows) continue;
            if (isU) {
                float* dst = U + (size_t)(pos0 + m) * NN + (col0 + tx * 4);
                *(float4*)dst = make_float4(acc[i][0], acc[i][1], acc[i][2], acc[i][3]);
            } else {
                float* dst = SH + (size_t)(pos0 + m) * HH + (col0 - 256 + tx * 4);
                float4 r;
                r.x = acc[i][0] * sigm(acc[i][0]);
                r.y = acc[i][1] * sigm(acc[i][1]);
                r.z = acc[i][2] * sigm(acc[i][2]);
                r.w = acc[i][3] * sigm(acc[i][3]);
                *(float4*)dst = r;
            }
        }
    } else if (mode == 1) {
        int region = col0 >> 8;          // 0:a 1:b 2:c 3:d
        int n0 = (col0 & 255) + tx * 4;
        #pragma unroll
        for (int i = 0; i < 4; i++) {
            int m = ty * 4 + i;
            if (m >= rows) continue;
            size_t idx = (size_t)(pos0 + m) * NN + n0;
            float4 r;
            if (region == 0) {
                r.x = sigm(acc[i][0]); r.y = sigm(acc[i][1]);
                r.z = sigm(acc[i][2]); r.w = sigm(acc[i][3]);
                *(float4*)(Aa + idx) = r;
            } else if (region == 1) {
                float4 uv = *(const float4*)(U + idx);
                r.x = tanhf(acc[i][0]) * uv.x; r.y = tanhf(acc[i][1]) * uv.y;
                r.z = tanhf(acc[i][2]) * uv.z; r.w = tanhf(acc[i][3]) * uv.w;
                *(float4*)(Wg + idx) = r;
            } else if (region == 2) {
                r.x = tanhf(acc[i][0]); r.y = tanhf(acc[i][1]);
                r.z = tanhf(acc[i][2]); r.w = tanhf(acc[i][3]);
                *(float4*)(Cc + idx) = r;
            } else {
                float4 uv = *(const float4*)(U + idx);
                float4 dp = *(const float4*)(dparam + e * 256 + n0);
                r.x = dp.x * sigm(acc[i][0]) * uv.x; r.y = dp.y * sigm(acc[i][1]) * uv.y;
                r.z = dp.z * sigm(acc[i][2]) * uv.z; r.w = dp.w * sigm(acc[i][3]) * uv.w;
                *(float4*)(Sk + idx) = r;
            }
        }
    } else {
        #pragma unroll
        for (int i = 0; i < 4; i++) {
            int m = ty * 4 + i;
            if (m >= rows) continue;
            int t = perm[pos0 + m];
            float* dst = out + (size_t)t * DD + (col0 + tx * 4);
            *(float4*)dst = make_float4(acc[i][0], acc[i][1], acc[i][2], acc[i][3]);
        }
    }
}

// ---------------- K6: per-(b,e) sequential scan ----------------
__global__ void k_scan(const float* __restrict__ Aa, const float* __restrict__ Wg,
                       const float* __restrict__ Cc, const float* __restrict__ Sk,
                       float* __restrict__ Y,
                       const int* __restrict__ grpoff, const int* __restrict__ cnt) {
    int g = blockIdx.x;
    int b = g >> 3, e = g & 7;
    int tid = threadIdx.x;
    int start = grpoff[b * 8 + e];
    int n = cnt[b * 8 + e];
    if (n == 0) return;
    float h = 0.0f;
    size_t idx = (size_t)start * NN + tid;
    float a = Aa[idx], w = Wg[idx], c = Cc[idx], sk = Sk[idx];
    for (int i = 0; i < n; i++) {
        size_t nidx = idx + NN;
        float a2 = 0.f, w2 = 0.f, c2 = 0.f, s2 = 0.f;
        if (i + 1 < n) {  // prefetch next step
            a2 = Aa[nidx]; w2 = Wg[nidx]; c2 = Cc[nidx]; s2 = Sk[nidx];
        }
        h = a * h + w;
        Y[idx] = c * h + sk;
        a = a2; w = w2; c = c2; sk = s2;
        idx = nidx;
    }
}

extern "C" void kernel_launch(void* const* d_in, const int* in_sizes, int n_in,
                              void* d_out, int out_size, void* d_ws, size_t ws_size,
                              hipStream_t stream) {
    const float* xin   = (const float*)d_in[0];
    const int*   tok   = (const int*)d_in[1];
    const float* Win   = (const float*)d_in[2];
    const float* Wsin  = (const float*)d_in[3];
    const float* Wsout = (const float*)d_in[4];
    const float* Wout  = (const float*)d_in[5];
    const float* dpar  = (const float*)d_in[6];
    float* out = (float*)d_out;

    size_t off = 0;
    char* base = (char*)d_ws;
    auto alloc = [&](size_t bytes) -> void* {
        void* p = base + off;
        off += (bytes + 255) & ~(size_t)255;
        return p;
    };
    float* U   = (float*)alloc((size_t)TOKS * NN * 4);   // 16 MB, reused as Y
    float* SH  = (float*)alloc((size_t)TOKS * HH * 4);   // 32 MB
    float* Aa  = (float*)alloc((size_t)TOKS * NN * 4);
    float* Wg  = (float*)alloc((size_t)TOKS * NN * 4);
    float* Cc  = (float*)alloc((size_t)TOKS * NN * 4);
    float* Sk  = (float*)alloc((size_t)TOKS * NN * 4);
    int* perm   = (int*)alloc(TOKS * 4);
    int* cnt    = (int*)alloc(64 * 4);
    int* grpoff = (int*)alloc(64 * 4);
    int* tileE  = (int*)alloc(272 * 4);
    int* tileS  = (int*)alloc(272 * 4);
    int* tileR  = (int*)alloc(272 * 4);
    int* meta   = (int*)alloc(16 * 4);

    k_route<<<8, 256, 0, stream>>>(tok, cnt);
    k_offsets<<<1, 64, 0, stream>>>(cnt, grpoff, tileE, tileS, tileR, meta);
    k_scatter<<<8, 256, 0, stream>>>(tok, grpoff, perm);

    // GEMM12: U (N=256) and SH=silu (H=512), 768 output cols -> 12 col tiles
    k_gemm<<<dim3(MAXTILES, 12), 256, 0, stream>>>(0, DD, xin, perm, Win, Wsin, Wsout, Wout,
        dpar, U, SH, Aa, Wg, Cc, Sk, out, tileE, tileS, tileR, meta);
    // GEMM3: 4N=1024 output cols -> 16 col tiles
    k_gemm<<<dim3(MAXTILES, 16), 256, 0, stream>>>(1, HH, xin, perm, Win, Wsin, Wsout, Wout,
        dpar, U, SH, Aa, Wg, Cc, Sk, out, tileE, tileS, tileR, meta);
    // scan: 64 groups (b,e)
    k_scan<<<64, 256, 0, stream>>>(Aa, Wg, Cc, Sk, U, grpoff, cnt);
    // GEMM4: D=1024 output cols -> 16 col tiles, scatter store
    k_gemm<<<dim3(MAXTILES, 16), 256, 0, stream>>>(2, NN, xin, perm, Win, Wsin, Wsout, Wout,
        dpar, U, SH, Aa, Wg, Cc, Sk, out, tileE, tileS, tileR, meta);
}

// Round 3
// 369.927 us; speedup vs baseline: 2.9103x; 2.9103x over previous
//
#include <hip/hip_runtime.h>

// HashRoutedSSMLayer: B=8,S=2048,D=1024,N=256,H=512,E=8 — fp32 in/out.
// Round 3: bf16 MFMA GEMMs (m97 structure: 128x128 tile, 16x16x32 mfma,
// global_load_lds 16B staging) + chunked 3-phase exact scan.

#define TOKS 16384
#define RPAD 16512      // TOKS + 128 pad rows for tile overread
#define DD   1024
#define NN   256
#define HH   512
#define MAXTILES  136   // sum ceil(ce/128) <= 128+8
#define MAXCHUNKS 1088  // sum ceil(n_g/16) <= 1024+64
#define CHUNK 16

typedef short short8 __attribute__((ext_vector_type(8)));
typedef float floatx4 __attribute__((ext_vector_type(4)));

#define AS_GLOBAL __attribute__((address_space(1)))
#define AS_LDS    __attribute__((address_space(3)))

__device__ __forceinline__ void gl_lds16(const void* g, void* l) {
    __builtin_amdgcn_global_load_lds((const AS_GLOBAL void*)g, (AS_LDS void*)l, 16, 0, 0);
}

__device__ __forceinline__ unsigned short f2bf(float f) {
    union { float f; unsigned u; } c; c.f = f;
    unsigned r = c.u + 0x7FFF + ((c.u >> 16) & 1);
    return (unsigned short)(r >> 16);
}
__device__ __forceinline__ int route_of(int token) {
    unsigned x = (unsigned)token;
    x ^= x >> 16; x *= 2246822507u; x ^= x >> 13; x *= 3266489909u; x ^= x >> 16;
    return (int)(x & 7u);
}
__device__ __forceinline__ float sigm(float v) { return 1.0f / (1.0f + __expf(-v)); }

// ---------------- K1: per-row route histogram ----------------
__global__ void k_route(const int* __restrict__ tok, int* __restrict__ cnt) {
    int b = blockIdx.x, tid = threadIdx.x;
    __shared__ int lc[256 * 8];
    #pragma unroll
    for (int e = 0; e < 8; e++) lc[tid * 8 + e] = 0;
    #pragma unroll
    for (int i = 0; i < 8; i++) {
        int e = route_of(tok[b * 2048 + tid * 8 + i]);
        lc[tid * 8 + e]++;
    }
    __syncthreads();
    if (tid < 8) {
        int s = 0;
        for (int t = 0; t < 256; t++) s += lc[t * 8 + tid];
        cnt[b * 8 + tid] = s;
    }
}

// ---------------- K2: offsets + tile table + chunk table ----------------
__global__ void k_offsets(const int* __restrict__ cnt, int* __restrict__ grpoff,
                          int* __restrict__ tileE, int* __restrict__ tileS,
                          int* __restrict__ tileR,
                          int* __restrict__ cGrp, int* __restrict__ cStart,
                          int* __restrict__ cLen, int* __restrict__ gBase,
                          int* __restrict__ meta) {
    __shared__ int sc[64], ce[8], eoff[9], etile[9], gb[65], go[64];
    int tid = threadIdx.x;
    if (tid < 64) sc[tid] = cnt[tid];
    __syncthreads();
    if (tid < 8) { int s = 0; for (int b = 0; b < 8; b++) s += sc[b * 8 + tid]; ce[tid] = s; }
    __syncthreads();
    if (tid == 0) {
        eoff[0] = 0; etile[0] = 0;
        for (int e = 0; e < 8; e++) {
            eoff[e + 1] = eoff[e] + ce[e];
            etile[e + 1] = etile[e] + (ce[e] + 127) / 128;
        }
        meta[0] = etile[8];
        gb[0] = 0;
        for (int g = 0; g < 64; g++) gb[g + 1] = gb[g] + (sc[g] + CHUNK - 1) / CHUNK;
        meta[1] = gb[64];
    }
    __syncthreads();
    if (tid < 64) {
        int b = tid >> 3, e = tid & 7;
        int run = eoff[e];
        for (int b2 = 0; b2 < b; b2++) run += sc[b2 * 8 + e];
        go[tid] = run;
        grpoff[tid] = run;
    }
    __syncthreads();
    if (tid < 8) {   // tiles for expert tid
        int e = tid, st = eoff[e], c = ce[e], t0 = etile[e];
        for (int i = 0, k = 0; i < c; i += 128, k++) {
            tileE[t0 + k] = e; tileS[t0 + k] = st + i;
            tileR[t0 + k] = (c - i < 128) ? (c - i) : 128;
        }
    }
    if (tid < 64) {  // chunks for group tid
        int g = tid, n = sc[g], base = gb[g], s0 = go[g];
        gBase[g] = base;
        for (int i = 0, c = 0; i < n; i += CHUNK, c++) {
            cGrp[base + c] = g;
            cStart[base + c] = s0 + i;
            cLen[base + c] = (n - i < CHUNK) ? (n - i) : CHUNK;
        }
    }
}

// ---------------- K3: stable counting-sort scatter ----------------
__global__ void k_scatter(const int* __restrict__ tok, const int* __restrict__ grpoff,
                          int* __restrict__ perm) {
    int b = blockIdx.x, tid = threadIdx.x;
    __shared__ int lh[8 * 256];
    int r[8];
    int myc[8] = {0,0,0,0,0,0,0,0};
    #pragma unroll
    for (int i = 0; i < 8; i++) {
        int e = route_of(tok[b * 2048 + tid * 8 + i]);
        r[i] = e; myc[e]++;
    }
    #pragma unroll
    for (int e = 0; e < 8; e++) lh[e * 256 + tid] = myc[e];
    __syncthreads();
    for (int e = 0; e < 8; e++) {
        for (int off = 1; off < 256; off <<= 1) {
            int add = (tid >= off) ? lh[e * 256 + tid - off] : 0;
            __syncthreads();
            lh[e * 256 + tid] += add;
            __syncthreads();
        }
    }
    int basep[8];
    #pragma unroll
    for (int e = 0; e < 8; e++) basep[e] = grpoff[b * 8 + e] + lh[e * 256 + tid] - myc[e];
    #pragma unroll
    for (int i = 0; i < 8; i++) {
        int e = r[i];
        perm[basep[e]++] = b * 2048 + tid * 8 + i;
    }
}

// ---------------- K4: weights fp32 -> bf16 (W12 = [Win|Wsin] concat) ----------------
__global__ void k_cvtw(const float* __restrict__ Win, const float* __restrict__ Wsin,
                       const float* __restrict__ Wsout, const float* __restrict__ Wout,
                       unsigned short* __restrict__ W12, unsigned short* __restrict__ Wso,
                       unsigned short* __restrict__ Wo) {
    const int C12 = 8 * 768 * 1024 / 4, CSO = 8 * 1024 * 512 / 4, CWO = 8 * 1024 * 256 / 4;
    int c = blockIdx.x * 256 + threadIdx.x;
    float4 v; unsigned short* dst;
    if (c < C12) {
        int d = c * 4;
        int e = d / (768 * 1024);
        int rem = d - e * (768 * 1024);
        int r = rem >> 10, k = rem & 1023;
        const float* src = (r < 256) ? (Win + (((size_t)e * 256 + r) << 10) + k)
                                     : (Wsin + (((size_t)e * 512 + (r - 256)) << 10) + k);
        v = *(const float4*)src;
        dst = W12 + d;
    } else if (c < C12 + CSO) {
        int d = (c - C12) * 4;
        v = *(const float4*)(Wsout + d);
        dst = Wso + d;
    } else if (c < C12 + CSO + CWO) {
        int d = (c - C12 - CSO) * 4;
        v = *(const float4*)(Wout + d);
        dst = Wo + d;
    } else return;
    ushort4 o;
    o.x = f2bf(v.x); o.y = f2bf(v.y); o.z = f2bf(v.z); o.w = f2bf(v.w);
    *(ushort4*)dst = o;
}

// ---------------- K5: gather x into sorted bf16 rows + zero pads ----------------
__global__ void k_gather(const float* __restrict__ x, const int* __restrict__ perm,
                         unsigned short* __restrict__ Xs, unsigned short* __restrict__ SHb,
                         unsigned short* __restrict__ Yb) {
    int r = blockIdx.x, t = threadIdx.x;
    if (r < TOKS) {
        int tok = perm[r];
        float4 v = *(const float4*)(x + (size_t)tok * 1024 + t * 4);
        ushort4 o;
        o.x = f2bf(v.x); o.y = f2bf(v.y); o.z = f2bf(v.z); o.w = f2bf(v.w);
        *(ushort4*)(Xs + (size_t)r * 1024 + t * 4) = o;
    } else {
        ushort4 z = {0, 0, 0, 0};
        *(ushort4*)(Xs + (size_t)r * 1024 + t * 4) = z;
        if (t < 128) *(ushort4*)(SHb + (size_t)r * 512 + t * 4) = z;
        if (t < 64)  *(ushort4*)(Yb + (size_t)r * 256 + t * 4) = z;
    }
}

// ---------------- K6/K7/K10: MFMA grouped GEMM ----------------
// MODE 0: A=Xs (K=1024), B=W12 [e][768][1024]: cols<256 -> U fp32; else silu -> SHb bf16
// MODE 1: A=SHb (K=512), B=Wso [e][1024][512]: regions a,b,c,d -> Aa,Wg,Cc,Sk fp32
// MODE 2: A=Yb (K=256),  B=Wo  [e][1024][256]: scatter fp32 out via perm
template<int MODE, int KD>
__global__ __launch_bounds__(256)
void k_mfma(const unsigned short* __restrict__ A, const unsigned short* __restrict__ Bw,
            const int* __restrict__ perm, const float* __restrict__ dparam,
            float* __restrict__ U, unsigned short* __restrict__ SHb,
            float* __restrict__ Aa, float* __restrict__ Wg,
            float* __restrict__ Cc, float* __restrict__ Sk,
            float* __restrict__ out,
            const int* __restrict__ tileE, const int* __restrict__ tileS,
            const int* __restrict__ tileR, const int* __restrict__ meta) {
    int mt = blockIdx.x;
    if (mt >= meta[0]) return;
    const int e = tileE[mt], pos0 = tileS[mt], rows = tileR[mt];
    const int col0 = blockIdx.y * 128;
    const int tid = threadIdx.x;
    const int w = tid >> 6, lane = tid & 63, quad = lane >> 4, l15 = lane & 15;
    const int wm = w & 1, wn = w >> 1;
    constexpr int NOUT = (MODE == 0) ? 768 : 1024;

    __shared__ unsigned short As[128 * 32];
    __shared__ unsigned short Bs[128 * 32];

    // staging: chunk c = q*256 + tid; row = c>>2; col = (c&3)*8 (bf16 elems)
    const int r0 = tid >> 2, c8 = (tid & 3) * 8;
    const unsigned short* ga = A + (size_t)(pos0 + r0) * KD + c8;
    const unsigned short* gb = Bw + ((size_t)e * NOUT + col0 + r0) * KD + c8;

    floatx4 acc[4][4] = {};

    // LDS frag offsets (bf16 elem index), fixed across K-loop
    int aoff[4], boff[4];
    #pragma unroll
    for (int i = 0; i < 4; i++) aoff[i] = (wm * 64 + i * 16 + l15) * 32 + quad * 8;
    #pragma unroll
    for (int j = 0; j < 4; j++) boff[j] = (wn * 64 + j * 16 + l15) * 32 + quad * 8;

    for (int k0 = 0; k0 < KD; k0 += 32) {
        __syncthreads();  // prior compute's LDS reads done
        gl_lds16(ga + k0,                      As + w * 512);
        gl_lds16(ga + (size_t)64 * KD + k0,    As + 2048 + w * 512);
        gl_lds16(gb + k0,                      Bs + w * 512);
        gl_lds16(gb + (size_t)64 * KD + k0,    Bs + 2048 + w * 512);
        __syncthreads();  // drains vmcnt: LDS tiles ready
        short8 af[4], bf[4];
        #pragma unroll
        for (int i = 0; i < 4; i++) af[i] = *(const short8*)(As + aoff[i]);
        #pragma unroll
        for (int j = 0; j < 4; j++) bf[j] = *(const short8*)(Bs + boff[j]);
        #pragma unroll
        for (int i = 0; i < 4; i++)
            #pragma unroll
            for (int j = 0; j < 4; j++)
                acc[i][j] = __builtin_amdgcn_mfma_f32_16x16x32_bf16(af[i], bf[j], acc[i][j], 0, 0, 0);
    }

    // epilogue: C/D layout: col = l15 (n), row = quad*4 + reg (m), per 16x16 tile
    #pragma unroll
    for (int i = 0; i < 4; i++) {
        #pragma unroll
        for (int r = 0; r < 4; r++) {
            int m = wm * 64 + i * 16 + quad * 4 + r;
            if (m >= rows) continue;
            size_t row = (size_t)(pos0 + m);
            if (MODE == 0) {
                if (col0 < 256) {
                    #pragma unroll
                    for (int j = 0; j < 4; j++) {
                        int n = col0 + wn * 64 + j * 16 + l15;
                        U[row * 256 + n] = acc[i][j][r];
                    }
                } else {
                    #pragma unroll
                    for (int j = 0; j < 4; j++) {
                        int n = col0 - 256 + wn * 64 + j * 16 + l15;
                        float v = acc[i][j][r];
                        SHb[row * 512 + n] = f2bf(v * sigm(v));
                    }
                }
            } else if (MODE == 1) {
                int region = col0 >> 8;  // block-uniform
                #pragma unroll
                for (int j = 0; j < 4; j++) {
                    int n0 = (col0 & 255) + wn * 64 + j * 16 + l15;
                    size_t idx = row * 256 + (size_t)(n0 & 255);
                    float v = acc[i][j][r];
                    if (region == 0) {
                        Aa[idx] = sigm(v);
                    } else if (region == 1) {
                        Wg[idx] = tanhf(v) * U[idx];
                    } else if (region == 2) {
                        Cc[idx] = tanhf(v);
                    } else {
                        Sk[idx] = dparam[e * 256 + (n0 & 255)] * sigm(v) * U[idx];
                    }
                }
            } else {
                int tok = perm[row];
                #pragma unroll
                for (int j = 0; j < 4; j++) {
                    int n = col0 + wn * 64 + j * 16 + l15;
                    out[(size_t)tok * 1024 + n] = acc[i][j][r];
                }
            }
        }
    }
}

// ---------------- K8a: chunk-local affine composition ----------------
__global__ void k_scanA(const float* __restrict__ Aa, const float* __restrict__ Wg,
                        const int* __restrict__ cStart, const int* __restrict__ cLen,
                        const int* __restrict__ meta,
                        float* __restrict__ SA, float* __restrict__ SQ) {
    int id = blockIdx.x;
    if (id >= meta[1]) return;
    int t = threadIdx.x;
    int s0 = cStart[id], L = cLen[id];
    size_t idx = (size_t)s0 * 256 + t;
    float p = 1.0f, q = 0.0f;
    for (int i = 0; i < L; i++) {
        float a = Aa[idx], ww = Wg[idx];
        q = a * q + ww;
        p *= a;
        idx += 256;
    }
    SA[(size_t)id * 256 + t] = p;
    SQ[(size_t)id * 256 + t] = q;
}

// ---------------- K8b: per-group serial combine -> chunk h_in ----------------
__global__ void k_scanB(const float* __restrict__ SA, const float* __restrict__ SQ,
                        const int* __restrict__ gBase, const int* __restrict__ cnt,
                        float* __restrict__ Hin) {
    int g = blockIdx.x, t = threadIdx.x;
    int base = gBase[g], nch = (cnt[g] + CHUNK - 1) / CHUNK;
    float h = 0.0f;
    for (int c = 0; c < nch; c++) {
        size_t k = (size_t)(base + c) * 256 + t;
        Hin[k] = h;
        h = SA[k] * h + SQ[k];
    }
}

// ---------------- K8c: re-scan with h_in, emit y (bf16) ----------------
__global__ void k_scanC(const float* __restrict__ Aa, const float* __restrict__ Wg,
                        const float* __restrict__ Cc, const float* __restrict__ Sk,
                        const int* __restrict__ cStart, const int* __restrict__ cLen,
                        const int* __restrict__ meta, const float* __restrict__ Hin,
                        unsigned short* __restrict__ Yb) {
    int id = blockIdx.x;
    if (id >= meta[1]) return;
    int t = threadIdx.x;
    int s0 = cStart[id], L = cLen[id];
    float h = Hin[(size_t)id * 256 + t];
    size_t idx = (size_t)s0 * 256 + t;
    for (int i = 0; i < L; i++) {
        float a = Aa[idx], ww = Wg[idx], c = Cc[idx], sk = Sk[idx];
        h = a * h + ww;
        Yb[idx] = f2bf(c * h + sk);
        idx += 256;
    }
}

extern "C" void kernel_launch(void* const* d_in, const int* in_sizes, int n_in,
                              void* d_out, int out_size, void* d_ws, size_t ws_size,
                              hipStream_t stream) {
    const float* xin   = (const float*)d_in[0];
    const int*   tok   = (const int*)d_in[1];
    const float* Win   = (const float*)d_in[2];
    const float* Wsin  = (const float*)d_in[3];
    const float* Wsout = (const float*)d_in[4];
    const float* Wout  = (const float*)d_in[5];
    const float* dpar  = (const float*)d_in[6];
    float* out = (float*)d_out;

    size_t off = 0;
    char* base = (char*)d_ws;
    auto alloc = [&](size_t bytes) -> void* {
        void* p = base + off;
        off += (bytes + 255) & ~(size_t)255;
        return p;
    };
    float*          U   = (float*)alloc((size_t)RPAD * NN * 4);
    unsigned short* SHb = (unsigned short*)alloc((size_t)RPAD * HH * 2);
    unsigned short* Xs  = (unsigned short*)alloc((size_t)RPAD * DD * 2);
    unsigned short* Yb  = (unsigned short*)alloc((size_t)RPAD * NN * 2);
    float* Aa = (float*)alloc((size_t)TOKS * NN * 4);
    float* Wg = (float*)alloc((size_t)TOKS * NN * 4);
    float* Cc = (float*)alloc((size_t)TOKS * NN * 4);
    float* Sk = (float*)alloc((size_t)TOKS * NN * 4);
    unsigned short* W12 = (unsigned short*)alloc((size_t)8 * 768 * 1024 * 2);
    unsigned short* Wso = (unsigned short*)alloc((size_t)8 * 1024 * 512 * 2);
    unsigned short* Wo  = (unsigned short*)alloc((size_t)8 * 1024 * 256 * 2);
    float* SA  = (float*)alloc((size_t)MAXCHUNKS * 256 * 4);
    float* SQ  = (float*)alloc((size_t)MAXCHUNKS * 256 * 4);
    float* Hin = (float*)alloc((size_t)MAXCHUNKS * 256 * 4);
    int* perm   = (int*)alloc(TOKS * 4);
    int* cnt    = (int*)alloc(64 * 4);
    int* grpoff = (int*)alloc(64 * 4);
    int* tileE  = (int*)alloc(MAXTILES * 4);
    int* tileS  = (int*)alloc(MAXTILES * 4);
    int* tileR  = (int*)alloc(MAXTILES * 4);
    int* cGrp   = (int*)alloc(MAXCHUNKS * 4);
    int* cStart = (int*)alloc(MAXCHUNKS * 4);
    int* cLen   = (int*)alloc(MAXCHUNKS * 4);
    int* gBase  = (int*)alloc(64 * 4);
    int* meta   = (int*)alloc(16 * 4);

    k_route<<<8, 256, 0, stream>>>(tok, cnt);
    k_offsets<<<1, 256, 0, stream>>>(cnt, grpoff, tileE, tileS, tileR,
                                     cGrp, cStart, cLen, gBase, meta);
    k_scatter<<<8, 256, 0, stream>>>(tok, grpoff, perm);
    k_cvtw<<<12288, 256, 0, stream>>>(Win, Wsin, Wsout, Wout, W12, Wso, Wo);
    k_gather<<<RPAD, 256, 0, stream>>>(xin, perm, Xs, SHb, Yb);

    k_mfma<0, 1024><<<dim3(MAXTILES, 6), 256, 0, stream>>>(Xs, W12, perm, dpar,
        U, SHb, Aa, Wg, Cc, Sk, out, tileE, tileS, tileR, meta);
    k_mfma<1, 512><<<dim3(MAXTILES, 8), 256, 0, stream>>>(SHb, Wso, perm, dpar,
        U, SHb, Aa, Wg, Cc, Sk, out, tileE, tileS, tileR, meta);

    k_scanA<<<MAXCHUNKS, 256, 0, stream>>>(Aa, Wg, cStart, cLen, meta, SA, SQ);
    k_scanB<<<64, 256, 0, stream>>>(SA, SQ, gBase, cnt, Hin);
    k_scanC<<<MAXCHUNKS, 256, 0, stream>>>(Aa, Wg, Cc, Sk, cStart, cLen, meta, Hin, Yb);

    k_mfma<2, 256><<<dim3(MAXTILES, 8), 256, 0, stream>>>(Yb, Wo, perm, dpar,
        U, SHb, Aa, Wg, Cc, Sk, out, tileE, tileS, tileR, meta);
}

// Round 4
// 322.852 us; speedup vs baseline: 3.3347x; 1.1458x over previous
//
#include <hip/hip_runtime.h>

// HashRoutedSSMLayer: B=8,S=2048,D=1024,N=256,H=512,E=8 — fp32 in/out.
// Round 4: BK=64 double-depth K-loop (32 MFMA per barrier pair), fast tanh,
// fp16 U/gates. Verified 16x16x32 bf16 MFMA fragment mapping from round 3.

#define TOKS 16384
#define RPAD 16512      // TOKS + 128 pad rows for tile overread
#define DD   1024
#define NN   256
#define HH   512
#define MAXTILES  136   // sum ceil(ce/128) <= 128+8
#define MAXCHUNKS 1088  // sum ceil(n_g/16) <= 1024+64
#define CHUNK 16

typedef short short8 __attribute__((ext_vector_type(8)));
typedef float floatx4 __attribute__((ext_vector_type(4)));
typedef _Float16 half_t;

#define AS_GLOBAL __attribute__((address_space(1)))
#define AS_LDS    __attribute__((address_space(3)))

__device__ __forceinline__ void gl_lds16(const void* g, void* l) {
    __builtin_amdgcn_global_load_lds((const AS_GLOBAL void*)g, (AS_LDS void*)l, 16, 0, 0);
}

__device__ __forceinline__ unsigned short f2bf(float f) {
    union { float f; unsigned u; } c; c.f = f;
    unsigned r = c.u + 0x7FFF + ((c.u >> 16) & 1);
    return (unsigned short)(r >> 16);
}
__device__ __forceinline__ int route_of(int token) {
    unsigned x = (unsigned)token;
    x ^= x >> 16; x *= 2246822507u; x ^= x >> 13; x *= 3266489909u; x ^= x >> 16;
    return (int)(x & 7u);
}
__device__ __forceinline__ float sigm(float v) { return 1.0f / (1.0f + __expf(-v)); }
__device__ __forceinline__ float ftanh(float v) {
    float e = __expf(2.0f * v);          // inf-safe: v>>0 -> 1, v<<0 -> -1
    return 1.0f - 2.0f / (e + 1.0f);
}

// ---------------- K1: per-row route histogram ----------------
__global__ void k_route(const int* __restrict__ tok, int* __restrict__ cnt) {
    int b = blockIdx.x, tid = threadIdx.x;
    __shared__ int lc[256 * 8];
    #pragma unroll
    for (int e = 0; e < 8; e++) lc[tid * 8 + e] = 0;
    #pragma unroll
    for (int i = 0; i < 8; i++) {
        int e = route_of(tok[b * 2048 + tid * 8 + i]);
        lc[tid * 8 + e]++;
    }
    __syncthreads();
    if (tid < 8) {
        int s = 0;
        for (int t = 0; t < 256; t++) s += lc[t * 8 + tid];
        cnt[b * 8 + tid] = s;
    }
}

// ---------------- K2: offsets + tile table + chunk table ----------------
__global__ void k_offsets(const int* __restrict__ cnt, int* __restrict__ grpoff,
                          int* __restrict__ tileE, int* __restrict__ tileS,
                          int* __restrict__ tileR,
                          int* __restrict__ cGrp, int* __restrict__ cStart,
                          int* __restrict__ cLen, int* __restrict__ gBase,
                          int* __restrict__ meta) {
    __shared__ int sc[64], ce[8], eoff[9], etile[9], gb[65], go[64];
    int tid = threadIdx.x;
    if (tid < 64) sc[tid] = cnt[tid];
    __syncthreads();
    if (tid < 8) { int s = 0; for (int b = 0; b < 8; b++) s += sc[b * 8 + tid]; ce[tid] = s; }
    __syncthreads();
    if (tid == 0) {
        eoff[0] = 0; etile[0] = 0;
        for (int e = 0; e < 8; e++) {
            eoff[e + 1] = eoff[e] + ce[e];
            etile[e + 1] = etile[e] + (ce[e] + 127) / 128;
        }
        meta[0] = etile[8];
        gb[0] = 0;
        for (int g = 0; g < 64; g++) gb[g + 1] = gb[g] + (sc[g] + CHUNK - 1) / CHUNK;
        meta[1] = gb[64];
    }
    __syncthreads();
    if (tid < 64) {
        int b = tid >> 3, e = tid & 7;
        int run = eoff[e];
        for (int b2 = 0; b2 < b; b2++) run += sc[b2 * 8 + e];
        go[tid] = run;
        grpoff[tid] = run;
    }
    __syncthreads();
    if (tid < 8) {   // tiles for expert tid
        int e = tid, st = eoff[e], c = ce[e], t0 = etile[e];
        for (int i = 0, k = 0; i < c; i += 128, k++) {
            tileE[t0 + k] = e; tileS[t0 + k] = st + i;
            tileR[t0 + k] = (c - i < 128) ? (c - i) : 128;
        }
    }
    if (tid < 64) {  // chunks for group tid
        int g = tid, n = sc[g], base = gb[g], s0 = go[g];
        gBase[g] = base;
        for (int i = 0, c = 0; i < n; i += CHUNK, c++) {
            cGrp[base + c] = g;
            cStart[base + c] = s0 + i;
            cLen[base + c] = (n - i < CHUNK) ? (n - i) : CHUNK;
        }
    }
}

// ---------------- K3: stable counting-sort scatter ----------------
__global__ void k_scatter(const int* __restrict__ tok, const int* __restrict__ grpoff,
                          int* __restrict__ perm) {
    int b = blockIdx.x, tid = threadIdx.x;
    __shared__ int lh[8 * 256];
    int r[8];
    int myc[8] = {0,0,0,0,0,0,0,0};
    #pragma unroll
    for (int i = 0; i < 8; i++) {
        int e = route_of(tok[b * 2048 + tid * 8 + i]);
        r[i] = e; myc[e]++;
    }
    #pragma unroll
    for (int e = 0; e < 8; e++) lh[e * 256 + tid] = myc[e];
    __syncthreads();
    for (int e = 0; e < 8; e++) {
        for (int off = 1; off < 256; off <<= 1) {
            int add = (tid >= off) ? lh[e * 256 + tid - off] : 0;
            __syncthreads();
            lh[e * 256 + tid] += add;
            __syncthreads();
        }
    }
    int basep[8];
    #pragma unroll
    for (int e = 0; e < 8; e++) basep[e] = grpoff[b * 8 + e] + lh[e * 256 + tid] - myc[e];
    #pragma unroll
    for (int i = 0; i < 8; i++) {
        int e = r[i];
        perm[basep[e]++] = b * 2048 + tid * 8 + i;
    }
}

// ---------------- K4: weights fp32 -> bf16 (W12 = [Win|Wsin] concat) ----------------
__global__ void k_cvtw(const float* __restrict__ Win, const float* __restrict__ Wsin,
                       const float* __restrict__ Wsout, const float* __restrict__ Wout,
                       unsigned short* __restrict__ W12, unsigned short* __restrict__ Wso,
                       unsigned short* __restrict__ Wo) {
    const int C12 = 8 * 768 * 1024 / 4, CSO = 8 * 1024 * 512 / 4, CWO = 8 * 1024 * 256 / 4;
    int c = blockIdx.x * 256 + threadIdx.x;
    float4 v; unsigned short* dst;
    if (c < C12) {
        int d = c * 4;
        int e = d / (768 * 1024);
        int rem = d - e * (768 * 1024);
        int r = rem >> 10, k = rem & 1023;
        const float* src = (r < 256) ? (Win + (((size_t)e * 256 + r) << 10) + k)
                                     : (Wsin + (((size_t)e * 512 + (r - 256)) << 10) + k);
        v = *(const float4*)src;
        dst = W12 + d;
    } else if (c < C12 + CSO) {
        int d = (c - C12) * 4;
        v = *(const float4*)(Wsout + d);
        dst = Wso + d;
    } else if (c < C12 + CSO + CWO) {
        int d = (c - C12 - CSO) * 4;
        v = *(const float4*)(Wout + d);
        dst = Wo + d;
    } else return;
    ushort4 o;
    o.x = f2bf(v.x); o.y = f2bf(v.y); o.z = f2bf(v.z); o.w = f2bf(v.w);
    *(ushort4*)dst = o;
}

// ---------------- K5: gather x into sorted bf16 rows + zero pads ----------------
__global__ void k_gather(const float* __restrict__ x, const int* __restrict__ perm,
                         unsigned short* __restrict__ Xs, unsigned short* __restrict__ SHb,
                         unsigned short* __restrict__ Yb) {
    int r = blockIdx.x, t = threadIdx.x;
    if (r < TOKS) {
        int tok = perm[r];
        float4 v = *(const float4*)(x + (size_t)tok * 1024 + t * 4);
        ushort4 o;
        o.x = f2bf(v.x); o.y = f2bf(v.y); o.z = f2bf(v.z); o.w = f2bf(v.w);
        *(ushort4*)(Xs + (size_t)r * 1024 + t * 4) = o;
    } else {
        ushort4 z = {0, 0, 0, 0};
        *(ushort4*)(Xs + (size_t)r * 1024 + t * 4) = z;
        if (t < 128) *(ushort4*)(SHb + (size_t)r * 512 + t * 4) = z;
        if (t < 64)  *(ushort4*)(Yb + (size_t)r * 256 + t * 4) = z;
    }
}

// ---------------- MFMA grouped GEMM, BM=128 BN=128 BK=64 ----------------
// MODE 0: A=Xs (K=1024), B=W12 [e][768][1024]: n<256 -> Ub fp16; else silu -> SHb bf16
// MODE 1: A=SHb (K=512), B=Wso [e][1024][512]: regions a,b,c,d -> fp16 gates
// MODE 2: A=Yb (K=256),  B=Wo  [e][1024][256]: scatter fp32 out via perm
template<int MODE, int KD>
__global__ __launch_bounds__(256, 3)
void k_mfma(const unsigned short* __restrict__ A, const unsigned short* __restrict__ Bw,
            const int* __restrict__ perm, const float* __restrict__ dparam,
            half_t* __restrict__ Ub, unsigned short* __restrict__ SHb,
            half_t* __restrict__ Aa, half_t* __restrict__ Wg,
            half_t* __restrict__ Cc, half_t* __restrict__ Sk,
            float* __restrict__ out,
            const int* __restrict__ tileE, const int* __restrict__ tileS,
            const int* __restrict__ tileR, const int* __restrict__ meta) {
    int mt = blockIdx.x;
    if (mt >= meta[0]) return;
    const int e = tileE[mt], pos0 = tileS[mt], rows = tileR[mt];
    const int col0 = blockIdx.y * 128;
    const int tid = threadIdx.x;
    const int w = tid >> 6, lane = tid & 63, quad = lane >> 4, l15 = lane & 15;
    const int wm = w & 1, wn = w >> 1;
    constexpr int NOUT = (MODE == 0) ? 768 : 1024;

    // [kb=2][row=128][32 elems] per operand
    __shared__ unsigned short As[2 * 128 * 32];
    __shared__ unsigned short Bs[2 * 128 * 32];

    const int r0 = tid >> 2, c8 = (tid & 3) * 8;
    const unsigned short* ga = A + (size_t)(pos0 + r0) * KD + c8;
    const unsigned short* gb = Bw + ((size_t)e * NOUT + col0 + r0) * KD + c8;

    floatx4 acc[4][4] = {};

    int aoff[4], boff[4];
    #pragma unroll
    for (int i = 0; i < 4; i++) aoff[i] = (wm * 64 + i * 16 + l15) * 32 + quad * 8;
    #pragma unroll
    for (int j = 0; j < 4; j++) boff[j] = (wn * 64 + j * 16 + l15) * 32 + quad * 8;

    for (int k0 = 0; k0 < KD; k0 += 64) {
        __syncthreads();  // prior compute's LDS reads done
        gl_lds16(ga + k0,                          As + w * 512);
        gl_lds16(ga + (size_t)64 * KD + k0,        As + 2048 + w * 512);
        gl_lds16(ga + k0 + 32,                     As + 4096 + w * 512);
        gl_lds16(ga + (size_t)64 * KD + k0 + 32,   As + 6144 + w * 512);
        gl_lds16(gb + k0,                          Bs + w * 512);
        gl_lds16(gb + (size_t)64 * KD + k0,        Bs + 2048 + w * 512);
        gl_lds16(gb + k0 + 32,                     Bs + 4096 + w * 512);
        gl_lds16(gb + (size_t)64 * KD + k0 + 32,   Bs + 6144 + w * 512);
        __syncthreads();  // drains vmcnt: both 32-K half tiles ready
        #pragma unroll
        for (int kb = 0; kb < 2; kb++) {
            short8 af[4], bf[4];
            #pragma unroll
            for (int i = 0; i < 4; i++) af[i] = *(const short8*)(As + kb * 4096 + aoff[i]);
            #pragma unroll
            for (int j = 0; j < 4; j++) bf[j] = *(const short8*)(Bs + kb * 4096 + boff[j]);
            #pragma unroll
            for (int i = 0; i < 4; i++)
                #pragma unroll
                for (int j = 0; j < 4; j++)
                    acc[i][j] = __builtin_amdgcn_mfma_f32_16x16x32_bf16(af[i], bf[j], acc[i][j], 0, 0, 0);
        }
    }

    // epilogue: C/D layout: col = l15 (n), row = quad*4 + reg (m), per 16x16 tile
    #pragma unroll
    for (int i = 0; i < 4; i++) {
        #pragma unroll
        for (int r = 0; r < 4; r++) {
            int m = wm * 64 + i * 16 + quad * 4 + r;
            if (m >= rows) continue;
            size_t row = (size_t)(pos0 + m);
            if (MODE == 0) {
                if (col0 < 256) {
                    #pragma unroll
                    for (int j = 0; j < 4; j++) {
                        int n = col0 + wn * 64 + j * 16 + l15;
                        Ub[row * 256 + n] = (half_t)acc[i][j][r];
                    }
                } else {
                    #pragma unroll
                    for (int j = 0; j < 4; j++) {
                        int n = col0 - 256 + wn * 64 + j * 16 + l15;
                        float v = acc[i][j][r];
                        SHb[row * 512 + n] = f2bf(v * sigm(v));
                    }
                }
            } else if (MODE == 1) {
                int region = col0 >> 8;  // block-uniform
                #pragma unroll
                for (int j = 0; j < 4; j++) {
                    int n0 = (col0 & 255) + wn * 64 + j * 16 + l15;
                    size_t idx = row * 256 + (size_t)n0;
                    float v = acc[i][j][r];
                    if (region == 0) {
                        Aa[idx] = (half_t)sigm(v);
                    } else if (region == 1) {
                        Wg[idx] = (half_t)(ftanh(v) * (float)Ub[idx]);
                    } else if (region == 2) {
                        Cc[idx] = (half_t)ftanh(v);
                    } else {
                        Sk[idx] = (half_t)(dparam[e * 256 + n0] * sigm(v) * (float)Ub[idx]);
                    }
                }
            } else {
                int tok = perm[row];
                #pragma unroll
                for (int j = 0; j < 4; j++) {
                    int n = col0 + wn * 64 + j * 16 + l15;
                    out[(size_t)tok * 1024 + n] = acc[i][j][r];
                }
            }
        }
    }
}

// ---------------- K8a: chunk-local affine composition ----------------
__global__ void k_scanA(const half_t* __restrict__ Aa, const half_t* __restrict__ Wg,
                        const int* __restrict__ cStart, const int* __restrict__ cLen,
                        const int* __restrict__ meta,
                        float* __restrict__ SA, float* __restrict__ SQ) {
    int id = blockIdx.x;
    if (id >= meta[1]) return;
    int t = threadIdx.x;
    int s0 = cStart[id], L = cLen[id];
    size_t idx = (size_t)s0 * 256 + t;
    float p = 1.0f, q = 0.0f;
    for (int i = 0; i < L; i++) {
        float a = (float)Aa[idx], ww = (float)Wg[idx];
        q = a * q + ww;
        p *= a;
        idx += 256;
    }
    SA[(size_t)id * 256 + t] = p;
    SQ[(size_t)id * 256 + t] = q;
}

// ---------------- K8b: per-group serial combine -> chunk h_in ----------------
__global__ void k_scanB(const float* __restrict__ SA, const float* __restrict__ SQ,
                        const int* __restrict__ gBase, const int* __restrict__ cnt,
                        float* __restrict__ Hin) {
    int g = blockIdx.x, t = threadIdx.x;
    int base = gBase[g], nch = (cnt[g] + CHUNK - 1) / CHUNK;
    float h = 0.0f;
    for (int c = 0; c < nch; c++) {
        size_t k = (size_t)(base + c) * 256 + t;
        Hin[k] = h;
        h = SA[k] * h + SQ[k];
    }
}

// ---------------- K8c: re-scan with h_in, emit y (bf16) ----------------
__global__ void k_scanC(const half_t* __restrict__ Aa, const half_t* __restrict__ Wg,
                        const half_t* __restrict__ Cc, const half_t* __restrict__ Sk,
                        const int* __restrict__ cStart, const int* __restrict__ cLen,
                        const int* __restrict__ meta, const float* __restrict__ Hin,
                        unsigned short* __restrict__ Yb) {
    int id = blockIdx.x;
    if (id >= meta[1]) return;
    int t = threadIdx.x;
    int s0 = cStart[id], L = cLen[id];
    float h = Hin[(size_t)id * 256 + t];
    size_t idx = (size_t)s0 * 256 + t;
    for (int i = 0; i < L; i++) {
        float a = (float)Aa[idx], ww = (float)Wg[idx];
        float c = (float)Cc[idx], sk = (float)Sk[idx];
        h = a * h + ww;
        Yb[idx] = f2bf(c * h + sk);
        idx += 256;
    }
}

extern "C" void kernel_launch(void* const* d_in, const int* in_sizes, int n_in,
                              void* d_out, int out_size, void* d_ws, size_t ws_size,
                              hipStream_t stream) {
    const float* xin   = (const float*)d_in[0];
    const int*   tok   = (const int*)d_in[1];
    const float* Win   = (const float*)d_in[2];
    const float* Wsin  = (const float*)d_in[3];
    const float* Wsout = (const float*)d_in[4];
    const float* Wout  = (const float*)d_in[5];
    const float* dpar  = (const float*)d_in[6];
    float* out = (float*)d_out;

    size_t off = 0;
    char* base = (char*)d_ws;
    auto alloc = [&](size_t bytes) -> void* {
        void* p = base + off;
        off += (bytes + 255) & ~(size_t)255;
        return p;
    };
    half_t*         Ub  = (half_t*)alloc((size_t)RPAD * NN * 2);
    unsigned short* SHb = (unsigned short*)alloc((size_t)RPAD * HH * 2);
    unsigned short* Xs  = (unsigned short*)alloc((size_t)RPAD * DD * 2);
    unsigned short* Yb  = (unsigned short*)alloc((size_t)RPAD * NN * 2);
    half_t* Aa = (half_t*)alloc((size_t)TOKS * NN * 2);
    half_t* Wg = (half_t*)alloc((size_t)TOKS * NN * 2);
    half_t* Cc = (half_t*)alloc((size_t)TOKS * NN * 2);
    half_t* Sk = (half_t*)alloc((size_t)TOKS * NN * 2);
    unsigned short* W12 = (unsigned short*)alloc((size_t)8 * 768 * 1024 * 2);
    unsigned short* Wso = (unsigned short*)alloc((size_t)8 * 1024 * 512 * 2);
    unsigned short* Wo  = (unsigned short*)alloc((size_t)8 * 1024 * 256 * 2);
    float* SA  = (float*)alloc((size_t)MAXCHUNKS * 256 * 4);
    float* SQ  = (float*)alloc((size_t)MAXCHUNKS * 256 * 4);
    float* Hin = (float*)alloc((size_t)MAXCHUNKS * 256 * 4);
    int* perm   = (int*)alloc(TOKS * 4);
    int* cnt    = (int*)alloc(64 * 4);
    int* grpoff = (int*)alloc(64 * 4);
    int* tileE  = (int*)alloc(MAXTILES * 4);
    int* tileS  = (int*)alloc(MAXTILES * 4);
    int* tileR  = (int*)alloc(MAXTILES * 4);
    int* cGrp   = (int*)alloc(MAXCHUNKS * 4);
    int* cStart = (int*)alloc(MAXCHUNKS * 4);
    int* cLen   = (int*)alloc(MAXCHUNKS * 4);
    int* gBase  = (int*)alloc(64 * 4);
    int* meta   = (int*)alloc(16 * 4);

    k_route<<<8, 256, 0, stream>>>(tok, cnt);
    k_offsets<<<1, 256, 0, stream>>>(cnt, grpoff, tileE, tileS, tileR,
                                     cGrp, cStart, cLen, gBase, meta);
    k_scatter<<<8, 256, 0, stream>>>(tok, grpoff, perm);
    k_cvtw<<<12288, 256, 0, stream>>>(Win, Wsin, Wsout, Wout, W12, Wso, Wo);
    k_gather<<<RPAD, 256, 0, stream>>>(xin, perm, Xs, SHb, Yb);

    k_mfma<0, 1024><<<dim3(MAXTILES, 6), 256, 0, stream>>>(Xs, W12, perm, dpar,
        Ub, SHb, Aa, Wg, Cc, Sk, out, tileE, tileS, tileR, meta);
    k_mfma<1, 512><<<dim3(MAXTILES, 8), 256, 0, stream>>>(SHb, Wso, perm, dpar,
        Ub, SHb, Aa, Wg, Cc, Sk, out, tileE, tileS, tileR, meta);

    k_scanA<<<MAXCHUNKS, 256, 0, stream>>>(Aa, Wg, cStart, cLen, meta, SA, SQ);
    k_scanB<<<64, 256, 0, stream>>>(SA, SQ, gBase, cnt, Hin);
    k_scanC<<<MAXCHUNKS, 256, 0, stream>>>(Aa, Wg, Cc, Sk, cStart, cLen, meta, Hin, Yb);

    k_mfma<2, 256><<<dim3(MAXTILES, 8), 256, 0, stream>>>(Yb, Wo, perm, dpar,
        Ub, SHb, Aa, Wg, Cc, Sk, out, tileE, tileS, tileR, meta);
}